// Round 2
// baseline (135.093 us; speedup 1.0000x reference)
//
#include <hip/hip_runtime.h>
#include <math.h>

#define B 8
#define SQ 128
#define SK 128
#define IVD 32
#define DIM 32
#define EV 64
#define H 8
#define NH 128
#define DK 8
#define TQ 2
#define KG 8      // k-groups in weighted-sum phase (16 k each)
#define PAD 132   // transposed leading dim: SK + 4 floats

__device__ __forceinline__ float fast_tanh(float x) {
    const float xc = fminf(fmaxf(x, -10.f), 10.f);
    const float t = __expf(2.f * xc);
    return (t - 1.f) / (t + 1.f);
}

// Single plain-launch kernel: 512 blocks x 256 threads, 2 blocks/CU (68.2 KB LDS)
// -> all 512 blocks co-resident, so the per-batch flag spin cannot deadlock.
// Phase A: block i projects q rows 2i,2i+1 (kept in LDS), k rows 2i,2i+1 ->
//          global kproj (+ release flag), impute rows 2i,2i+1 -> qd, stages
//          value/mask tiles.
// spin:    wait for the 64 sentinel flags of this batch (acquire).
// Phase B: masked-softmax attention + output GEMV for the block's own 2 q rows.
__global__ __launch_bounds__(256, 2) void fused_all(
    const float* __restrict__ qv, const float* __restrict__ kv,
    const float* __restrict__ value, const int* __restrict__ mask,
    const float* __restrict__ imp,
    const float* __restrict__ w1, const float* __restrict__ b1,
    const float* __restrict__ w2,
    const float* __restrict__ wq, const float* __restrict__ bqv,
    const float* __restrict__ wk, const float* __restrict__ bkv,
    const float* __restrict__ wo, const float* __restrict__ bo,
    const float* __restrict__ wd1, const float* __restrict__ bd1,
    const float* __restrict__ ln_g, const float* __restrict__ ln_b,
    const float* __restrict__ wd2, const float* __restrict__ bd2,
    float* __restrict__ y, float* __restrict__ qd,
    float* __restrict__ kproj, unsigned long long* __restrict__ flags)
{
    const int blk = blockIdx.x;           // 0..511
    const int b = blk >> 6;               // batch
    const int q0 = (blk & 63) * TQ;       // this block's q rows within batch
    const int r0 = blk * 2;               // global row pair (q-, k-, impute-space)
    const int tid = threadIdx.x;
    const int half = tid >> 7;            // two 128-thread teams
    const int t = tid & 127;

    // sentinel: two DIFFERENT 32-bit words -> cannot alias any repeated
    // 32-bit poison fill pattern in the workspace.
    const unsigned long long MAGIC = 0x85EBCA6B9E3779B9ull;

    // ---- phase B shared (persists across the spin) ----
    __shared__ __align__(16) float qs[TQ * EV];        // pre-scaled q rows
    __shared__ __align__(16) float sc[TQ * H * SK];    // exp'd scores
    __shared__ __align__(16) float mvt[DIM * PAD];     // (mask*value)^T [d][k]
    __shared__ __align__(16) float mmt[DIM * PAD];     // mask^T         [d][k]
    __shared__ __align__(16) float2 part[H * KG * DIM];// per-q partials (16 KB)
    __shared__ __align__(16) float xr[TQ * H * DIM];   // attn out rows
    __shared__ __align__(16) float ypart[2 * TQ * NH];
    // ---- phase A shared ----
    __shared__ float xs[2][2][IVD];
    __shared__ float h1[2][2][NH];
    __shared__ float ev[2][2][EV];
    __shared__ float pA[2][2][128];
    __shared__ float xs2[2][IVD / 2];
    __shared__ float h1b[2][NH];
    __shared__ float redm[2][2];
    __shared__ float redv[2][2];

    // ================= PHASE A =================
    // value/mask staging (independent of projections)
    for (int idx = tid; idx < SK * DIM; idx += 256) {
        const int k = idx >> 5, d = idx & 31;
        const float v = value[b * SK * DIM + idx];
        const float m = (float)mask[b * SK * DIM + idx];
        mvt[d * PAD + k] = v * m;
        mmt[d * PAD + k] = m;
    }

    // projections: team 0 -> q pair (to LDS qs), team 1 -> k pair (to global kproj)
    {
        const float* src = half ? kv : qv;
        const float* wp  = half ? wk : wq;
        const float* bp  = half ? bkv : bqv;

        if (t < 2 * IVD) xs[half][t >> 5][t & 31] = src[r0 * IVD + t];
        __syncthreads();

        // GEMV1: h1 = tanh(x @ w1 + b1)
        float a0 = b1[t], a1 = a0;
        #pragma unroll
        for (int i = 0; i < IVD; ++i) {
            const float w = w1[i * NH + t];
            a0 += xs[half][0][i] * w; a1 += xs[half][1][i] * w;
        }
        h1[half][0][t] = fast_tanh(a0);
        h1[half][1][t] = fast_tanh(a1);
        __syncthreads();

        const int o = t & 63, hf = t >> 6;
        // GEMV2: ev = h1 @ w2 (dot split in 2 halves)
        {
            float c0 = 0.f, c1 = 0.f;
            #pragma unroll 8
            for (int i = hf * 64; i < hf * 64 + 64; ++i) {
                const float w = w2[i * EV + o];
                c0 += h1[half][0][i] * w; c1 += h1[half][1][i] * w;
            }
            pA[half][0][t] = c0; pA[half][1][t] = c1;
        }
        __syncthreads();
        {
            const int row = t >> 6, oo = t & 63;
            ev[half][row][oo] = pA[half][row][oo] + pA[half][row][oo + 64];
        }
        __syncthreads();
        // GEMV3: out = ev @ wp + bp
        {
            float c0 = 0.f, c1 = 0.f;
            #pragma unroll 8
            for (int j = hf * 32; j < hf * 32 + 32; ++j) {
                const float w = wp[j * EV + o];
                c0 += ev[half][0][j] * w; c1 += ev[half][1][j] * w;
            }
            pA[half][0][t] = c0; pA[half][1][t] = c1;
        }
        __syncthreads();
        {
            const int row = t >> 6, oo = t & 63;
            const float res = pA[half][row][oo] + pA[half][row][oo + 64] + bp[oo];
            if (half == 0) qs[row * EV + oo] = res * 0.3535533905932738f;
            else           kproj[(r0 + row) * EV + oo] = res;
        }
    }
    // publish this block's k rows ASAP (before impute) so consumers rarely wait.
    __syncthreads();   // drain kproj stores from all lanes (vmcnt before barrier)
    if (tid == 0) {
        __builtin_amdgcn_fence(__ATOMIC_RELEASE, "agent");
        __hip_atomic_store(&flags[blk], MAGIC, __ATOMIC_RELAXED,
                           __HIP_MEMORY_SCOPE_AGENT);
    }

    // impute path: row = r0 + half, out col = t (128 threads per row)
    {
        if (tid < IVD) xs2[tid >> 4][tid & 15] = imp[r0 * (IVD / 2) + tid];
        __syncthreads();
        float a = bd1[t];
        #pragma unroll
        for (int i = 0; i < IVD / 2; ++i)
            a += xs2[half][i] * wd1[i * NH + t];

        float s = a;
        #pragma unroll
        for (int off = 32; off > 0; off >>= 1) s += __shfl_down(s, off, 64);
        if ((t & 63) == 0) redm[half][t >> 6] = s;
        __syncthreads();
        const float mu = (redm[half][0] + redm[half][1]) * (1.f / NH);
        const float d = a - mu;
        float v2 = d * d;
        #pragma unroll
        for (int off = 32; off > 0; off >>= 1) v2 += __shfl_down(v2, off, 64);
        if ((t & 63) == 0) redv[half][t >> 6] = v2;
        __syncthreads();
        const float var = (redv[half][0] + redv[half][1]) * (1.f / NH);

        h1b[half][t] = fmaxf(d * rsqrtf(var + 1e-5f) * ln_g[t] + ln_b[t], 0.f);
        __syncthreads();

        float c = bd2[t];
        #pragma unroll 8
        for (int j = 0; j < NH; ++j)
            c += h1b[half][j] * wd2[j * NH + t];
        qd[(r0 + half) * NH + t] = c;
    }

    // ---- wait for all 64 k-producer blocks of this batch ----
    {
        const unsigned long long* fb = flags + b * 64;
        const int lane = tid & 63;
        for (int it = 0; it < (1 << 22); ++it) {   // bounded: fail visibly, not hang
            const unsigned long long v = __hip_atomic_load(
                &fb[lane], __ATOMIC_RELAXED, __HIP_MEMORY_SCOPE_AGENT);
            if (__all(v == MAGIC)) break;
            __builtin_amdgcn_s_sleep(2);
        }
        __builtin_amdgcn_fence(__ATOMIC_ACQUIRE, "agent");
    }
    __syncthreads();

    // ================= PHASE B =================
    // scores -> exp directly (no max subtraction: |s| bounded ~O(10), f32-safe,
    // ratios identical to reference softmax)
    #pragma unroll
    for (int i = 0; i < (TQ * H * SK) / 256; ++i) {
        const int p = tid + i * 256;
        const int q = p >> 10, rem = p & 1023, h = rem >> 7, k = rem & 127;
        const float4* kr = (const float4*)(kproj + (b * SK + k) * EV + h * DK);
        const float4* qq = (const float4*)(qs + q * EV + h * DK);
        const float4 k0 = kr[0], k1 = kr[1], qa = qq[0], qb = qq[1];
        const float s = qa.x * k0.x + qa.y * k0.y + qa.z * k0.z + qa.w * k0.w
                      + qb.x * k1.x + qb.y * k1.y + qb.z * k1.z + qb.w * k1.w;
        sc[p] = __expf(s);
    }
    __syncthreads();

    // weighted masked sums: thread owns (d, kg) -> value/mask slice in registers
    {
        const int d = tid & 31, kg = tid >> 5;
        float4 vv[4], mq[4];
        const float4* vp = (const float4*)&mvt[d * PAD + kg * 16];
        const float4* mp = (const float4*)&mmt[d * PAD + kg * 16];
        #pragma unroll
        for (int j = 0; j < 4; ++j) { vv[j] = vp[j]; mq[j] = mp[j]; }

        #pragma unroll
        for (int q = 0; q < TQ; ++q) {
            #pragma unroll
            for (int h = 0; h < H; ++h) {
                const float4* sp = (const float4*)&sc[(q * H + h) * SK + kg * 16];
                float num = 0.f, den = 0.f;
                #pragma unroll
                for (int j = 0; j < 4; ++j) {
                    const float4 s = sp[j];
                    num += s.x * vv[j].x + s.y * vv[j].y + s.z * vv[j].z + s.w * vv[j].w;
                    den += s.x * mq[j].x + s.y * mq[j].y + s.z * mq[j].z + s.w * mq[j].w;
                }
                part[(h * KG + kg) * DIM + d] = make_float2(num, den);
            }
            __syncthreads();
            {   // reduce 8 k-groups; thread -> (h = tid>>5, d = tid&31)
                const int h = tid >> 5;
                float num = 0.f, den = 0.f;
                #pragma unroll
                for (int g = 0; g < KG; ++g) {
                    const float2 p2 = part[(h * KG + g) * DIM + d];
                    num += p2.x; den += p2.y;
                }
                xr[q * (H * DIM) + tid] = num / den;
            }
            __syncthreads();
        }
    }

    // y = x @ wo + bo : 256-dot split in halves, wo load shared across TQ rows
    {
        const int n = tid & 127, hh = tid >> 7;
        const float* wop = wo + hh * 128 * NH + n;
        const float* x0 = xr + hh * 128;
        const float* x1 = xr + (H * DIM) + hh * 128;
        float a0 = 0.f, a1 = 0.f;
        #pragma unroll 4
        for (int j = 0; j < 128; ++j) {
            const float w = wop[j * NH];
            a0 += w * x0[j];
            a1 += w * x1[j];
        }
        ypart[hh * (TQ * NH) + 0 * NH + n] = a0;
        ypart[hh * (TQ * NH) + 1 * NH + n] = a1;
    }
    __syncthreads();
    {
        const int q = tid >> 7, n = tid & 127;
        y[(b * SQ + q0 + q) * NH + n] =
            ypart[q * NH + n] + ypart[TQ * NH + q * NH + n] + bo[n];
    }
}

extern "C" void kernel_launch(void* const* d_in, const int* in_sizes, int n_in,
                              void* d_out, int out_size, void* d_ws, size_t ws_size,
                              hipStream_t stream) {
    const float* query_value = (const float*)d_in[0];
    const float* key_value   = (const float*)d_in[1];
    const float* value       = (const float*)d_in[2];
    const float* impute      = (const float*)d_in[3];
    const int*   emb_mask    = (const int*)d_in[4];
    const float* w1   = (const float*)d_in[5];
    const float* b1   = (const float*)d_in[6];
    const float* w2   = (const float*)d_in[7];
    const float* wq   = (const float*)d_in[8];
    const float* bq   = (const float*)d_in[9];
    const float* wk   = (const float*)d_in[10];
    const float* bk   = (const float*)d_in[11];
    const float* wo   = (const float*)d_in[12];
    const float* bo   = (const float*)d_in[13];
    const float* wd1  = (const float*)d_in[14];
    const float* bd1  = (const float*)d_in[15];
    const float* ln_g = (const float*)d_in[16];
    const float* ln_b = (const float*)d_in[17];
    const float* wd2  = (const float*)d_in[18];
    const float* bd2  = (const float*)d_in[19];

    float* y  = (float*)d_out;                 // (B,SQ,NH)
    float* qd = y + B * SQ * NH;               // (B,SQ,NH)

    float* kproj = (float*)d_ws;               // (B,SK,EV) — cross-block tensor
    unsigned long long* flags =
        (unsigned long long*)((char*)d_ws + B * SK * EV * sizeof(float)); // 512 flags

    hipLaunchKernelGGL(fused_all, dim3(512), dim3(256), 0, stream,
                       query_value, key_value, value, emb_mask, impute,
                       w1, b1, w2, wq, bq, wk, bk, wo, bo,
                       wd1, bd1, ln_g, ln_b, wd2, bd2,
                       y, qd, kproj, flags);
}

// Round 3
// 120.908 us; speedup vs baseline: 1.1173x; 1.1173x over previous
//
#include <hip/hip_runtime.h>
#include <math.h>

#define B 8
#define SQ 128
#define SK 128
#define IVD 32
#define DIM 32
#define EV 64
#define H 8
#define NH 128
#define DK 8
#define KG 8      // k-groups in weighted-sum phase (16 k each)
#define PAD 132   // transposed leading dim: SK + 4 floats

__device__ __forceinline__ float fast_tanh(float x) {
    const float xc = fminf(fmaxf(x, -10.f), 10.f);
    const float t = __expf(2.f * xc);
    return (t - 1.f) / (t + 1.f);
}

// ---------------- Kernel 1: k projection only (the only cross-block tensor) ----
// 512 blocks x 128 threads, 2 k-rows per block. Exact round-0 arithmetic.
__global__ __launch_bounds__(128) void kproj_kernel(
    const float* __restrict__ kv,
    const float* __restrict__ w1, const float* __restrict__ b1,
    const float* __restrict__ w2,
    const float* __restrict__ wk, const float* __restrict__ bkv,
    float* __restrict__ kout)
{
    const int r = blockIdx.x;          // 0..511
    const int tid = threadIdx.x;
    const int row0 = r * 2;            // flat k-row over B*SK = 1024

    __shared__ float xs[2][IVD];
    __shared__ float h1[2][NH];
    __shared__ float ev[2][EV];
    __shared__ float part[2][128];

    if (tid < 2 * IVD) xs[tid >> 5][tid & 31] = kv[row0 * IVD + tid];
    __syncthreads();

    // GEMV1: h1 = tanh(x @ w1 + b1)
    {
        float a0 = b1[tid], a1 = a0;
        #pragma unroll
        for (int i = 0; i < IVD; ++i) {
            const float w = w1[i * NH + tid];
            a0 += xs[0][i] * w; a1 += xs[1][i] * w;
        }
        h1[0][tid] = fast_tanh(a0);
        h1[1][tid] = fast_tanh(a1);
    }
    __syncthreads();

    const int o = tid & 63, hf = tid >> 6;
    // GEMV2: ev = h1 @ w2 (dot split in 2 halves)
    {
        float c0 = 0.f, c1 = 0.f;
        #pragma unroll 8
        for (int i = hf * 64; i < hf * 64 + 64; ++i) {
            const float w = w2[i * EV + o];
            c0 += h1[0][i] * w; c1 += h1[1][i] * w;
        }
        part[0][tid] = c0; part[1][tid] = c1;
    }
    __syncthreads();
    {
        const int row = tid >> 6, oo = tid & 63;
        ev[row][oo] = part[row][oo] + part[row][oo + 64];
    }
    __syncthreads();
    // GEMV3: kout = ev @ wk + bk
    {
        float c0 = 0.f, c1 = 0.f;
        #pragma unroll 8
        for (int j = hf * 32; j < hf * 32 + 32; ++j) {
            const float w = wk[j * EV + o];
            c0 += ev[0][j] * w; c1 += ev[1][j] * w;
        }
        part[0][tid] = c0; part[1][tid] = c1;
    }
    __syncthreads();
    {
        const int row = tid >> 6, oo = tid & 63;
        kout[(row0 + row) * EV + oo] = part[row][oo] + part[row][oo + 64] + bkv[oo];
    }
}

// ---------------- Kernel 2: q-proj + impute + attention + output GEMV ----------
// 1024 blocks x 256 threads, 1 q-row per block. ~33.5 KB LDS -> 4 blocks/CU
// (16 waves/CU). Team 0 (tid<128): q projection. Team 1: impute path.
// All barriers are outside team conditionals (wave-uniform team split).
__global__ __launch_bounds__(256, 4) void attn_kernel(
    const float* __restrict__ qv, const float* __restrict__ kproj,
    const float* __restrict__ value, const int* __restrict__ mask,
    const float* __restrict__ imp,
    const float* __restrict__ w1, const float* __restrict__ b1,
    const float* __restrict__ w2,
    const float* __restrict__ wq, const float* __restrict__ bqv,
    const float* __restrict__ wo, const float* __restrict__ bo,
    const float* __restrict__ wd1, const float* __restrict__ bd1,
    const float* __restrict__ ln_g, const float* __restrict__ ln_b,
    const float* __restrict__ wd2, const float* __restrict__ bd2,
    float* __restrict__ y, float* __restrict__ qd)
{
    const int blk = blockIdx.x;        // 0..1023 == flat (b, q) row
    const int b = blk >> 7;
    const int tid = threadIdx.x;
    const int team = tid >> 7;         // 0: q-proj, 1: impute
    const int t = tid & 127;

    __shared__ __align__(16) float qs[EV];          // pre-scaled q row
    __shared__ __align__(16) float sc[H * SK];      // exp'd scores (4 KB)
    __shared__ __align__(16) float mvt[DIM * PAD];  // (mask*value)^T [d][k] (16.9 KB)
    __shared__ __align__(16) float2 part[4 * KG * DIM]; // PV partials, 4-head pass (8 KB)
    __shared__ __align__(16) float xr[H * DIM];     // attn out row
    __shared__ __align__(16) float ypart[2][NH];
    // phase A
    __shared__ float xs[IVD];
    __shared__ float h1[NH];
    __shared__ float ev[EV];
    __shared__ float pPA[128];
    __shared__ float xs2[IVD / 2];
    __shared__ float h1b[NH];
    __shared__ float redm[2], redv[2];

    const int d = tid & 31, kg = tid >> 5;   // PV ownership

    // ---- seg0: stage (mask*value)^T; load x rows ----
    for (int idx = tid; idx < SK * DIM; idx += 256) {
        const int k = idx >> 5, dd = idx & 31;
        mvt[dd * PAD + k] = value[b * SK * DIM + idx] * (float)mask[b * SK * DIM + idx];
    }
    if (team == 0) { if (t < IVD)     xs[t]  = qv[blk * IVD + t]; }
    else           { if (t < IVD / 2) xs2[t] = imp[blk * (IVD / 2) + t]; }
    __syncthreads();

    // ---- seg1: team0 GEMV1->h1 ; team1 impute GEMV1 + mean reduce ----
    float impA = 0.f;
    if (team == 0) {
        float a = b1[t];
        #pragma unroll
        for (int i = 0; i < IVD; ++i) a += xs[i] * w1[i * NH + t];
        h1[t] = fast_tanh(a);
    } else {
        float a = bd1[t];
        #pragma unroll
        for (int i = 0; i < IVD / 2; ++i) a += xs2[i] * wd1[i * NH + t];
        impA = a;
        float s = a;
        #pragma unroll
        for (int off = 32; off > 0; off >>= 1) s += __shfl_down(s, off, 64);
        if ((t & 63) == 0) redm[t >> 6] = s;
    }
    __syncthreads();

    // ---- seg2: team0 GEMV2 partials ; team1 variance reduce ----
    float impD = 0.f;
    if (team == 0) {
        const int o = t & 63, hf = t >> 6;
        float c = 0.f;
        #pragma unroll 8
        for (int i = hf * 64; i < hf * 64 + 64; ++i) c += h1[i] * w2[i * EV + o];
        pPA[t] = c;
    } else {
        const float mu = (redm[0] + redm[1]) * (1.f / NH);
        impD = impA - mu;
        float v2 = impD * impD;
        #pragma unroll
        for (int off = 32; off > 0; off >>= 1) v2 += __shfl_down(v2, off, 64);
        if ((t & 63) == 0) redv[t >> 6] = v2;
    }
    __syncthreads();

    // ---- seg3: team0 combine -> ev ; team1 layernorm+relu -> h1b ----
    if (team == 0) {
        if (t < EV) ev[t] = pPA[t] + pPA[t + 64];
    } else {
        const float var = (redv[0] + redv[1]) * (1.f / NH);
        h1b[t] = fmaxf(impD * rsqrtf(var + 1e-5f) * ln_g[t] + ln_b[t], 0.f);
    }
    __syncthreads();

    // ---- seg4: team0 GEMV3 partials ; team1 impute GEMV2 -> qd ----
    if (team == 0) {
        const int o = t & 63, hf = t >> 6;
        float c = 0.f;
        #pragma unroll 8
        for (int j = hf * 32; j < hf * 32 + 32; ++j) c += ev[j] * wq[j * EV + o];
        pPA[t] = c;
    } else {
        float c = bd2[t];
        #pragma unroll 8
        for (int j = 0; j < NH; ++j) c += h1b[j] * wd2[j * NH + t];
        qd[blk * NH + t] = c;
    }
    __syncthreads();

    // ---- seg5: q row -> qs (pre-scaled) ----
    if (team == 0 && t < EV)
        qs[t] = (pPA[t] + pPA[t + 64] + bqv[t]) * 0.3535533905932738f;
    __syncthreads();

    // mask bits for this thread's (d, kg) slice -> exact 0.0/1.0 floats.
    // Issued here so the loads overlap with the scores phase.
    float4 mq[4];
    {
        const int* mb = mask + b * SK * DIM + d;
        #pragma unroll
        for (int j = 0; j < 4; ++j) {
            const int k0 = kg * 16 + j * 4;
            mq[j] = make_float4((float)mb[(k0 + 0) * DIM], (float)mb[(k0 + 1) * DIM],
                                (float)mb[(k0 + 2) * DIM], (float)mb[(k0 + 3) * DIM]);
        }
    }

    // ---- scores -> exp (identical arithmetic to verified kernel) ----
    #pragma unroll
    for (int i = 0; i < (H * SK) / 256; ++i) {
        const int p = tid + i * 256;
        const int h = p >> 7, k = p & 127;
        const float4* kr = (const float4*)(kproj + (b * SK + k) * EV + h * DK);
        const float4* qq = (const float4*)(qs + h * DK);
        const float4 k0 = kr[0], k1 = kr[1], qa = qq[0], qb = qq[1];
        sc[p] = __expf(qa.x * k0.x + qa.y * k0.y + qa.z * k0.z + qa.w * k0.w
                     + qb.x * k1.x + qb.y * k1.y + qb.z * k1.z + qb.w * k1.w);
    }
    __syncthreads();

    // ---- PV: weighted masked sums, two 4-head passes (halves part LDS) ----
    float4 vv[4];
    {
        const float4* vp = (const float4*)&mvt[d * PAD + kg * 16];
        #pragma unroll
        for (int j = 0; j < 4; ++j) vv[j] = vp[j];
    }
    #pragma unroll
    for (int hp = 0; hp < 2; ++hp) {
        #pragma unroll
        for (int hl = 0; hl < 4; ++hl) {
            const int h = hp * 4 + hl;
            const float4* sp = (const float4*)&sc[h * SK + kg * 16];
            float num = 0.f, den = 0.f;
            #pragma unroll
            for (int j = 0; j < 4; ++j) {
                const float4 s = sp[j];
                num += s.x * vv[j].x + s.y * vv[j].y + s.z * vv[j].z + s.w * vv[j].w;
                den += s.x * mq[j].x + s.y * mq[j].y + s.z * mq[j].z + s.w * mq[j].w;
            }
            part[(hl * KG + kg) * DIM + d] = make_float2(num, den);
        }
        __syncthreads();
        if (kg < 4) {   // tid < 128: hl = kg
            const int hl = kg;
            float num = 0.f, den = 0.f;
            #pragma unroll
            for (int g = 0; g < KG; ++g) {
                const float2 p2 = part[(hl * KG + g) * DIM + d];
                num += p2.x; den += p2.y;
            }
            xr[(hp * 4 + hl) * DIM + d] = num / den;
        }
        __syncthreads();
    }

    // ---- y = x @ wo + bo (dot split in halves) ----
    {
        const int n = tid & 127, hh = tid >> 7;
        const float* wop = wo + hh * 128 * NH + n;
        const float* x0 = xr + hh * 128;
        float a = 0.f;
        #pragma unroll 4
        for (int j = 0; j < 128; ++j) a += wop[j * NH] * x0[j];
        ypart[hh][n] = a;
    }
    __syncthreads();
    if (tid < NH)
        y[blk * NH + tid] = ypart[0][tid] + ypart[1][tid] + bo[tid];
}

extern "C" void kernel_launch(void* const* d_in, const int* in_sizes, int n_in,
                              void* d_out, int out_size, void* d_ws, size_t ws_size,
                              hipStream_t stream) {
    const float* query_value = (const float*)d_in[0];
    const float* key_value   = (const float*)d_in[1];
    const float* value       = (const float*)d_in[2];
    const float* impute      = (const float*)d_in[3];
    const int*   emb_mask    = (const int*)d_in[4];
    const float* w1   = (const float*)d_in[5];
    const float* b1   = (const float*)d_in[6];
    const float* w2   = (const float*)d_in[7];
    const float* wq   = (const float*)d_in[8];
    const float* bq   = (const float*)d_in[9];
    const float* wk   = (const float*)d_in[10];
    const float* bk   = (const float*)d_in[11];
    const float* wo   = (const float*)d_in[12];
    const float* bo   = (const float*)d_in[13];
    const float* wd1  = (const float*)d_in[14];
    const float* bd1  = (const float*)d_in[15];
    const float* ln_g = (const float*)d_in[16];
    const float* ln_b = (const float*)d_in[17];
    const float* wd2  = (const float*)d_in[18];
    const float* bd2  = (const float*)d_in[19];

    float* y  = (float*)d_out;                 // (B,SQ,NH)
    float* qd = y + B * SQ * NH;               // (B,SQ,NH)

    float* kproj = (float*)d_ws;               // (B,SK,EV)

    hipLaunchKernelGGL(kproj_kernel, dim3(B * SK / 2), dim3(128), 0, stream,
                       key_value, w1, b1, w2, wk, bk, kproj);
    hipLaunchKernelGGL(attn_kernel, dim3(B * SQ), dim3(256), 0, stream,
                       query_value, kproj, value, emb_mask, impute,
                       w1, b1, w2, wq, bq, wo, bo,
                       wd1, bd1, ln_g, ln_b, wd2, bd2, y, qd);
}